// Round 2
// baseline (281.822 us; speedup 1.0000x reference)
//
#include <hip/hip_runtime.h>
#include <hip/hip_bf16.h>

#define BD 4
#define CD 96
#define OD 96
#define HD 128
#define WD 128
#define HWD (HD*WD)          // 16384

typedef __attribute__((ext_vector_type(8))) short bfrag;   // 8 bf16 (4 VGPRs)
typedef __attribute__((ext_vector_type(4))) float ffrag;   // 4 fp32 acc

__device__ __forceinline__ short f2bs(float f) {
    __hip_bfloat16 h = __float2bfloat16(f);
    return *reinterpret_cast<short*>(&h);
}

// XCD-aware swizzle for 1024-block launches (round-robin dispatch over 8 XCDs):
// XCD k owns 128 consecutive logical blocks = 64 consecutive image rows ->
// tap/gather halos stay in its 4 MiB L2.
__device__ __forceinline__ int swizzle1024(int gid) {
    return ((gid & 7) << 7) | (gid >> 3);
}

// ---------------------------------------------------------------------------
// Transpose: x (NCHW fp32) -> xb16 (pixel-major NHWC bf16)
// ---------------------------------------------------------------------------
__global__ __launch_bounds__(256) void k_transpose(const float* __restrict__ x,
                                                   short* __restrict__ xb16) {
    __shared__ short tile[128 * 104];
    int pix0 = blockIdx.x * 128;
    int b = pix0 / HWD; int hw0 = pix0 % HWD;
    int tid = threadIdx.x;

    for (int e = tid; e < 96*32; e += 256) {
        int c = e >> 5, g = e & 31;
        float4 v = *(const float4*)(x + ((size_t)(b*96 + c))*HWD + hw0 + 4*g);
        tile[(4*g+0)*104 + c] = f2bs(v.x);
        tile[(4*g+1)*104 + c] = f2bs(v.y);
        tile[(4*g+2)*104 + c] = f2bs(v.z);
        tile[(4*g+3)*104 + c] = f2bs(v.w);
    }
    __syncthreads();
    for (int e = tid; e < 128*12; e += 256) {
        int px = e / 12, c8 = e % 12;
        bfrag v = *(const bfrag*)(tile + px*104 + c8*8);
        *(bfrag*)(xb16 + ((size_t)(pix0 + px))*96 + c8*8) = v;
    }
}

// ---------------------------------------------------------------------------
// Repack weights to bf16 MFMA B-frag layouts (k = tap*96 + c):
//   wB1 (864x96): dconv_w   wB2 (864x32, o<18): off_w   wB (864x96): def_w
//   order: w[((s*NT+nt)*64 + l)*8 + j] = B[k=32s+(l>>4)*8+j][o=16nt+(l&15)]
// ---------------------------------------------------------------------------
__global__ void k_repack(const float* __restrict__ dconv_w,
                         const float* __restrict__ off_w,
                         const float* __restrict__ def_w,
                         short* __restrict__ wB1,
                         short* __restrict__ wB2,
                         short* __restrict__ wB) {
    int t = blockIdx.x * blockDim.x + threadIdx.x;
    if (t < 27648) {              // 864 x 32, NT=2
        int j = t & 7; int l = (t >> 3) & 63; int tile = t >> 9;
        int s = tile >> 1, nt = tile & 1;
        int k = 32*s + (l >> 4)*8 + j;
        int o = 16*nt + (l & 15);
        int c = k % 96, tap = k / 96;
        wB2[t] = (o < 18) ? f2bs(off_w[(o*96 + c)*9 + tap]) : (short)0;
    }
    if (t < 82944) {              // 864 x 96, NT=6
        int j = t & 7; int l = (t >> 3) & 63; int tile = t >> 9;
        int s = tile / 6, nt = tile % 6;
        int k = 32*s + (l >> 4)*8 + j;
        int o = 16*nt + (l & 15);
        int c = k % 96, tap = k / 96;
        wB1[t] = f2bs(dconv_w[(o*96 + c)*9 + tap]);
        wB[t]  = f2bs(def_w [(o*96 + c)*9 + tap]);
    }
}

// ---------------------------------------------------------------------------
// Kernel 1 (M=32/wave): x3b = bf16(x + relu(conv3x3 dil2 pad2(x))), NHWC
// Block = 64 px, TWO waves (128 thr); wave owns 32 px as two 16-px m-tiles
// sharing every B-fragment (round-0 per-pixel weight traffic) while the
// 1024-block grid gives 8 blocks/CU -> 4 waves/SIMD (round-1 occupancy).
// ---------------------------------------------------------------------------
__global__ __launch_bounds__(128, 4) void k_conv1(const float* __restrict__ x,
                                                  const short* __restrict__ xb16,
                                                  const short* __restrict__ wB,
                                                  const float* __restrict__ bias,
                                                  short* __restrict__ x3b) {
    int pix0 = swizzle1024(blockIdx.x) * 64;
    int b = pix0 / HWD; int hw0 = pix0 % HWD;
    int h = hw0 / WD; int w0 = hw0 % WD;
    int tid = threadIdx.x;
    int l = tid & 63, wv = tid >> 6;          // wv in {0,1}
    int q = l >> 4, mr = l & 15;
    int wq = w0 + 32*wv;
    const short* xb = xb16 + ((size_t)b * HWD) * 96;
    const bfrag az = {0,0,0,0,0,0,0,0};

    ffrag acc[2][6];
    #pragma unroll
    for (int mt = 0; mt < 2; mt++)
        #pragma unroll
        for (int nt = 0; nt < 6; nt++) acc[mt][nt] = ffrag{0.f,0.f,0.f,0.f};

    #pragma unroll 1
    for (int tap = 0; tap < 9; tap++) {
        int y = h + (tap/3)*2 - 2;
        if ((unsigned)y >= HD) continue;
        const short* abase[2]; bool vx[2];
        #pragma unroll
        for (int mt = 0; mt < 2; mt++) {
            int xx = wq + 16*mt + mr + (tap%3)*2 - 2;
            int xxc = min(max(xx, 0), WD-1);
            vx[mt] = (unsigned)xx < WD;
            abase[mt] = xb + ((size_t)(y*WD + xxc))*96 + q*8;
        }
        #pragma unroll
        for (int sc = 0; sc < 3; sc++) {
            const short* wb = wB + ((size_t)((tap*3+sc)*6)*64 + l)*8;
            bfrag bb[6];
            #pragma unroll
            for (int nt = 0; nt < 6; nt++) bb[nt] = *(const bfrag*)(wb + nt*512);
            #pragma unroll
            for (int mt = 0; mt < 2; mt++) {
                bfrag a = *(const bfrag*)(abase[mt] + sc*32);
                if (!vx[mt]) a = az;
                #pragma unroll
                for (int nt = 0; nt < 6; nt++)
                    acc[mt][nt] = __builtin_amdgcn_mfma_f32_16x16x32_bf16(a, bb[nt], acc[mt][nt], 0, 0, 0);
            }
        }
    }

    #pragma unroll
    for (int mt = 0; mt < 2; mt++) {
        int hwb = hw0 + 32*wv + 16*mt + q*4;
        #pragma unroll
        for (int nt = 0; nt < 6; nt++) {
            int o = 16*nt + mr;
            float bo = bias[o];
            float4 xr = *(const float4*)(x + ((size_t)(b*96 + o))*HWD + hwb);
            short* op = x3b + ((size_t)(b*HWD + hwb))*96 + o;
            op[0]   = f2bs(xr.x + fmaxf(acc[mt][nt][0] + bo, 0.f));
            op[96]  = f2bs(xr.y + fmaxf(acc[mt][nt][1] + bo, 0.f));
            op[192] = f2bs(xr.z + fmaxf(acc[mt][nt][2] + bo, 0.f));
            op[288] = f2bs(xr.w + fmaxf(acc[mt][nt][3] + bo, 0.f));
        }
    }
}

// ---------------------------------------------------------------------------
// Kernel 2 (fused, M=32/wave): conv2-MFMA -> offsets (5KB LDS, no barriers)
// -> bilinear gather (registers) -> deform MFMA (B-frags shared across the
// two m-tiles) -> out.  Block = 64 px, 2 waves; 1024 blocks -> 8 blocks/CU.
// ---------------------------------------------------------------------------
__global__ __launch_bounds__(128, 4) void k_deform(const short* __restrict__ x3b,
                                                   const short* __restrict__ wB2,
                                                   const float* __restrict__ off_b,
                                                   const short* __restrict__ wB,
                                                   const float* __restrict__ def_b,
                                                   float* __restrict__ out) {
    __shared__ float offsb[64][20];

    int pix0 = swizzle1024(blockIdx.x) * 64;
    int b = pix0 / HWD; int hw0 = pix0 % HWD;
    int h = hw0 / WD; int w0 = hw0 % WD;
    int tid = threadIdx.x;
    int l = tid & 63, wv = tid >> 6;          // wv in {0,1}
    int q = l >> 4, mr = l & 15;
    int wq = 32*wv;
    const short* xb = x3b + ((size_t)b * HWD) * 96;
    const bfrag az = {0,0,0,0,0,0,0,0};

    // ---- conv2 via MFMA: offsets for this wave's 32 pixels ----
    ffrag oa[2][2];
    #pragma unroll
    for (int mt = 0; mt < 2; mt++)
        #pragma unroll
        for (int nt = 0; nt < 2; nt++) oa[mt][nt] = ffrag{0.f,0.f,0.f,0.f};

    #pragma unroll 1
    for (int tap = 0; tap < 9; tap++) {
        int y = h + tap/3 - 1;
        if ((unsigned)y >= HD) continue;
        const short* abase[2]; bool vx[2];
        #pragma unroll
        for (int mt = 0; mt < 2; mt++) {
            int xx = w0 + wq + 16*mt + mr + tap%3 - 1;
            int xxc = min(max(xx, 0), WD-1);
            vx[mt] = (unsigned)xx < WD;
            abase[mt] = xb + ((size_t)(y*WD + xxc))*96 + q*8;
        }
        #pragma unroll
        for (int sc = 0; sc < 3; sc++) {
            const short* wb = wB2 + ((size_t)((tap*3+sc)*2)*64 + l)*8;
            bfrag b0 = *(const bfrag*)(wb);
            bfrag b1 = *(const bfrag*)(wb + 512);
            #pragma unroll
            for (int mt = 0; mt < 2; mt++) {
                bfrag a = *(const bfrag*)(abase[mt] + sc*32);
                if (!vx[mt]) a = az;
                oa[mt][0] = __builtin_amdgcn_mfma_f32_16x16x32_bf16(a, b0, oa[mt][0], 0, 0, 0);
                oa[mt][1] = __builtin_amdgcn_mfma_f32_16x16x32_bf16(a, b1, oa[mt][1], 0, 0, 0);
            }
        }
    }
    #pragma unroll
    for (int mt = 0; mt < 2; mt++) {
        int row = wq + 16*mt + q*4;
        float bo0 = off_b[mr];
        #pragma unroll
        for (int r = 0; r < 4; r++) offsb[row + r][mr] = oa[mt][0][r] + bo0;
        if (mr < 2) {
            float bo1 = off_b[16 + mr];
            #pragma unroll
            for (int r = 0; r < 4; r++) offsb[row + r][16 + mr] = oa[mt][1][r] + bo1;
        }
    }
    // no __syncthreads: offsb rows wq..wq+31 produced & consumed by wave wv

    // ---- gather + deform MFMA ----
    ffrag acc[2][6];
    #pragma unroll
    for (int mt = 0; mt < 2; mt++)
        #pragma unroll
        for (int nt = 0; nt < 6; nt++) acc[mt][nt] = ffrag{0.f,0.f,0.f,0.f};

    #pragma unroll 1
    for (int tap = 0; tap < 9; tap++) {
        const short* pp[2][4];
        float fb[2][4];
        #pragma unroll
        for (int mt = 0; mt < 2; mt++) {
            int lp = wq + 16*mt + mr;          // local pixel row in offsb
            int w = w0 + lp;                   // global x coordinate
            float dy = offsb[lp][2*tap];
            float dx = offsb[lp][2*tap + 1];
            float py  = (float)(h + tap/3 - 1) + dy;
            float pxf = (float)(w + tap%3 - 1) + dx;
            float y0f = floorf(py), x0f = floorf(pxf);
            float wy = py - y0f, wx = pxf - x0f;
            int y0 = (int)y0f, x0 = (int)x0f;
            int y1 = y0 + 1, x1 = x0 + 1;
            bool vy0 = (unsigned)y0 < HD, vy1 = (unsigned)y1 < HD;
            bool vx0 = (unsigned)x0 < WD, vx1 = (unsigned)x1 < WD;
            fb[mt][0] = (vy0 && vx0) ? (1.f-wy)*(1.f-wx) : 0.f;
            fb[mt][1] = (vy0 && vx1) ? (1.f-wy)*wx       : 0.f;
            fb[mt][2] = (vy1 && vx0) ? wy*(1.f-wx)       : 0.f;
            fb[mt][3] = (vy1 && vx1) ? wy*wx             : 0.f;
            int yc0 = min(max(y0,0),HD-1), yc1 = min(max(y1,0),HD-1);
            int xc0 = min(max(x0,0),WD-1), xc1 = min(max(x1,0),WD-1);
            pp[mt][0] = xb + ((size_t)(yc0*WD + xc0))*96 + q*8;
            pp[mt][1] = xb + ((size_t)(yc0*WD + xc1))*96 + q*8;
            pp[mt][2] = xb + ((size_t)(yc1*WD + xc0))*96 + q*8;
            pp[mt][3] = xb + ((size_t)(yc1*WD + xc1))*96 + q*8;
        }
        #pragma unroll
        for (int sc = 0; sc < 3; sc++) {
            int s = tap*3 + sc;
            const short* wb = wB + ((size_t)(s*6)*64 + l)*8;
            bfrag bbf[6];
            #pragma unroll
            for (int nt = 0; nt < 6; nt++) bbf[nt] = *(const bfrag*)(wb + nt*512);
            #pragma unroll
            for (int mt = 0; mt < 2; mt++) {
                bfrag c00 = *(const bfrag*)(pp[mt][0] + sc*32);
                bfrag c01 = *(const bfrag*)(pp[mt][1] + sc*32);
                bfrag c10 = *(const bfrag*)(pp[mt][2] + sc*32);
                bfrag c11 = *(const bfrag*)(pp[mt][3] + sc*32);
                const int* i00 = (const int*)&c00;
                const int* i01 = (const int*)&c01;
                const int* i10 = (const int*)&c10;
                const int* i11 = (const int*)&c11;
                float f00 = fb[mt][0], f01 = fb[mt][1];
                float f10 = fb[mt][2], f11 = fb[mt][3];
                int ap[4];
                #pragma unroll
                for (int d = 0; d < 4; d++) {
                    float a0 = __int_as_float(((unsigned)i00[d]) << 16);
                    float b0f = __int_as_float(((unsigned)i01[d]) << 16);
                    float c0f = __int_as_float(((unsigned)i10[d]) << 16);
                    float d0 = __int_as_float(((unsigned)i11[d]) << 16);
                    float a1 = __int_as_float(i00[d] & 0xffff0000);
                    float b1f = __int_as_float(i01[d] & 0xffff0000);
                    float c1f = __int_as_float(i10[d] & 0xffff0000);
                    float d1 = __int_as_float(i11[d] & 0xffff0000);
                    float rlo = f00*a0 + f01*b0f + f10*c0f + f11*d0;
                    float rhi = f00*a1 + f01*b1f + f10*c1f + f11*d1;
                    ap[d] = (int)((unsigned short)f2bs(rlo)) |
                            ((int)((unsigned short)f2bs(rhi)) << 16);
                }
                bfrag a = *(const bfrag*)ap;
                #pragma unroll
                for (int nt = 0; nt < 6; nt++)
                    acc[mt][nt] = __builtin_amdgcn_mfma_f32_16x16x32_bf16(a, bbf[nt], acc[mt][nt], 0, 0, 0);
            }
        }
    }

    // ---- epilogue: NCHW fp32 out, float4 per (m-tile, n-tile) ----
    #pragma unroll
    for (int mt = 0; mt < 2; mt++) {
        int hwb = hw0 + wq + 16*mt + q*4;
        #pragma unroll
        for (int nt = 0; nt < 6; nt++) {
            int o = 16*nt + mr;
            float bo = def_b[o];
            float4 v;
            v.x = acc[mt][nt][0] + bo; v.y = acc[mt][nt][1] + bo;
            v.z = acc[mt][nt][2] + bo; v.w = acc[mt][nt][3] + bo;
            *(float4*)(out + ((size_t)(b*96 + o))*HWD + hwb) = v;
        }
    }
}

// ---------------------------------------------------------------------------
// Workspace layout (bytes):
//   xb16 : 0        .. 12582912   (B*HW*96 bf16, NHWC of x)
//   x3b  : 12582912 .. 25165824   (B*HW*96 bf16, NHWC of x3)
//   wB1  : 25165824 .. 25331712
//   wB2  : 25331712 .. 25387008
//   wB   : 25387008 .. 25552896
// ---------------------------------------------------------------------------
extern "C" void kernel_launch(void* const* d_in, const int* in_sizes, int n_in,
                              void* d_out, int out_size, void* d_ws, size_t ws_size,
                              hipStream_t stream) {
    const float* x       = (const float*)d_in[0];
    const float* dconv_w = (const float*)d_in[1];
    const float* dconv_b = (const float*)d_in[2];
    const float* off_w   = (const float*)d_in[3];
    const float* off_b   = (const float*)d_in[4];
    const float* def_w   = (const float*)d_in[5];
    const float* def_b   = (const float*)d_in[6];
    float* out = (float*)d_out;

    char* ws = (char*)d_ws;
    short* xb16 = (short*)(ws);
    short* x3b  = (short*)(ws + 12582912);
    short* wB1  = (short*)(ws + 25165824);
    short* wB2  = (short*)(ws + 25331712);
    short* wB   = (short*)(ws + 25387008);

    k_repack<<<324, 256, 0, stream>>>(dconv_w, off_w, def_w, wB1, wB2, wB);
    k_transpose<<<(BD*HWD)/128, 256, 0, stream>>>(x, xb16);
    k_conv1<<<(BD*HWD)/64, 128, 0, stream>>>(x, xb16, wB1, dconv_b, x3b);
    k_deform<<<(BD*HWD)/64, 128, 0, stream>>>(x3b, wB2, off_b, wB, def_b, out);
}

// Round 3
// 272.564 us; speedup vs baseline: 1.0340x; 1.0340x over previous
//
#include <hip/hip_runtime.h>
#include <hip/hip_bf16.h>

#define BD 4
#define CD 96
#define OD 96
#define HD 128
#define WD 128
#define HWD (HD*WD)          // 16384

typedef __attribute__((ext_vector_type(8))) short bfrag;   // 8 bf16 (4 VGPRs)
typedef __attribute__((ext_vector_type(4))) float ffrag;   // 4 fp32 acc

__device__ __forceinline__ short f2bs(float f) {
    __hip_bfloat16 h = __float2bfloat16(f);
    return *reinterpret_cast<short*>(&h);
}

// XCD-aware swizzle for 1024-block launches (round-robin dispatch over 8 XCDs):
// XCD k owns 128 consecutive logical blocks = 64 consecutive image rows ->
// tap/gather halos stay in its 4 MiB L2.
__device__ __forceinline__ int swizzle1024(int gid) {
    return ((gid & 7) << 7) | (gid >> 3);
}

// ---------------------------------------------------------------------------
// Transpose: x (NCHW fp32) -> xb16 (pixel-major NHWC bf16)
// ---------------------------------------------------------------------------
__global__ __launch_bounds__(256) void k_transpose(const float* __restrict__ x,
                                                   short* __restrict__ xb16) {
    __shared__ short tile[128 * 104];
    int pix0 = blockIdx.x * 128;
    int b = pix0 / HWD; int hw0 = pix0 % HWD;
    int tid = threadIdx.x;

    for (int e = tid; e < 96*32; e += 256) {
        int c = e >> 5, g = e & 31;
        float4 v = *(const float4*)(x + ((size_t)(b*96 + c))*HWD + hw0 + 4*g);
        tile[(4*g+0)*104 + c] = f2bs(v.x);
        tile[(4*g+1)*104 + c] = f2bs(v.y);
        tile[(4*g+2)*104 + c] = f2bs(v.z);
        tile[(4*g+3)*104 + c] = f2bs(v.w);
    }
    __syncthreads();
    for (int e = tid; e < 128*12; e += 256) {
        int px = e / 12, c8 = e % 12;
        bfrag v = *(const bfrag*)(tile + px*104 + c8*8);
        *(bfrag*)(xb16 + ((size_t)(pix0 + px))*96 + c8*8) = v;
    }
}

// ---------------------------------------------------------------------------
// Repack weights to bf16 MFMA B-frag layouts (k = tap*96 + c):
//   wB1 (864x96): dconv_w   wB2 (864x32, o<18): off_w   wB (864x96): def_w
//   order: w[((s*NT+nt)*64 + l)*8 + j] = B[k=32s+(l>>4)*8+j][o=16nt+(l&15)]
// ---------------------------------------------------------------------------
__global__ void k_repack(const float* __restrict__ dconv_w,
                         const float* __restrict__ off_w,
                         const float* __restrict__ def_w,
                         short* __restrict__ wB1,
                         short* __restrict__ wB2,
                         short* __restrict__ wB) {
    int t = blockIdx.x * blockDim.x + threadIdx.x;
    if (t < 27648) {              // 864 x 32, NT=2
        int j = t & 7; int l = (t >> 3) & 63; int tile = t >> 9;
        int s = tile >> 1, nt = tile & 1;
        int k = 32*s + (l >> 4)*8 + j;
        int o = 16*nt + (l & 15);
        int c = k % 96, tap = k / 96;
        wB2[t] = (o < 18) ? f2bs(off_w[(o*96 + c)*9 + tap]) : (short)0;
    }
    if (t < 82944) {              // 864 x 96, NT=6
        int j = t & 7; int l = (t >> 3) & 63; int tile = t >> 9;
        int s = tile / 6, nt = tile % 6;
        int k = 32*s + (l >> 4)*8 + j;
        int o = 16*nt + (l & 15);
        int c = k % 96, tap = k / 96;
        wB1[t] = f2bs(dconv_w[(o*96 + c)*9 + tap]);
        wB[t]  = f2bs(def_w [(o*96 + c)*9 + tap]);
    }
}

// ---------------------------------------------------------------------------
// Kernel 1 (M=32/wave, TAP-SPLIT): x3b = bf16(x + relu(conv3x3 dil2 pad2(x)))
// Block = 64 px, 4 waves = 2 pairs. Pair p owns px 32p..32p+31 (two 16-px
// m-tiles sharing every B-frag = round-0 traffic). Within a pair, wave tg=0
// accumulates taps 0-3, tg=1 taps 4-8; partial acc summed via LDS.
// 1024 blocks * 4 waves = 4096 waves -> 16 waves/CU = 4 waves/SIMD.
// ---------------------------------------------------------------------------
__global__ __launch_bounds__(256, 4) void k_conv1(const float* __restrict__ x,
                                                  const short* __restrict__ xb16,
                                                  const short* __restrict__ wB,
                                                  const float* __restrict__ bias,
                                                  short* __restrict__ x3b) {
    __shared__ float4 accbuf[2][12][64];          // 24.5 KB partial-acc exchange

    int pix0 = swizzle1024(blockIdx.x) * 64;
    int b = pix0 / HWD; int hw0 = pix0 % HWD;
    int h = hw0 / WD; int w0 = hw0 % WD;
    int tid = threadIdx.x;
    int l = tid & 63, wv = tid >> 6;
    int p = wv >> 1, tg = wv & 1;                 // pair, tap-group
    int q = l >> 4, mr = l & 15;
    int wq = w0 + 32*p;
    int t0 = tg ? 4 : 0, t1 = tg ? 9 : 4;
    const short* xb = xb16 + ((size_t)b * HWD) * 96;
    const bfrag az = {0,0,0,0,0,0,0,0};

    ffrag acc[2][6];
    #pragma unroll
    for (int mt = 0; mt < 2; mt++)
        #pragma unroll
        for (int nt = 0; nt < 6; nt++) acc[mt][nt] = ffrag{0.f,0.f,0.f,0.f};

    #pragma unroll 1
    for (int tap = t0; tap < t1; tap++) {
        int y = h + (tap/3)*2 - 2;
        if ((unsigned)y >= HD) continue;
        const short* abase[2]; bool vx[2];
        #pragma unroll
        for (int mt = 0; mt < 2; mt++) {
            int xx = wq + 16*mt + mr + (tap%3)*2 - 2;
            int xxc = min(max(xx, 0), WD-1);
            vx[mt] = (unsigned)xx < WD;
            abase[mt] = xb + ((size_t)(y*WD + xxc))*96 + q*8;
        }
        #pragma unroll
        for (int sc = 0; sc < 3; sc++) {
            const short* wb = wB + ((size_t)((tap*3+sc)*6)*64 + l)*8;
            bfrag bb[6];
            #pragma unroll
            for (int nt = 0; nt < 6; nt++) bb[nt] = *(const bfrag*)(wb + nt*512);
            #pragma unroll
            for (int mt = 0; mt < 2; mt++) {
                bfrag a = *(const bfrag*)(abase[mt] + sc*32);
                if (!vx[mt]) a = az;
                #pragma unroll
                for (int nt = 0; nt < 6; nt++)
                    acc[mt][nt] = __builtin_amdgcn_mfma_f32_16x16x32_bf16(a, bb[nt], acc[mt][nt], 0, 0, 0);
            }
        }
    }

    if (tg) {
        #pragma unroll
        for (int mt = 0; mt < 2; mt++)
            #pragma unroll
            for (int nt = 0; nt < 6; nt++)
                accbuf[p][mt*6+nt][l] = float4{acc[mt][nt][0], acc[mt][nt][1],
                                               acc[mt][nt][2], acc[mt][nt][3]};
    }
    __syncthreads();
    if (!tg) {
        #pragma unroll
        for (int mt = 0; mt < 2; mt++) {
            int hwb = hw0 + 32*p + 16*mt + q*4;
            #pragma unroll
            for (int nt = 0; nt < 6; nt++) {
                float4 s = accbuf[p][mt*6+nt][l];
                int o = 16*nt + mr;
                float bo = bias[o];
                float4 xr = *(const float4*)(x + ((size_t)(b*96 + o))*HWD + hwb);
                short* op = x3b + ((size_t)(b*HWD + hwb))*96 + o;
                op[0]   = f2bs(xr.x + fmaxf(acc[mt][nt][0] + s.x + bo, 0.f));
                op[96]  = f2bs(xr.y + fmaxf(acc[mt][nt][1] + s.y + bo, 0.f));
                op[192] = f2bs(xr.z + fmaxf(acc[mt][nt][2] + s.z + bo, 0.f));
                op[288] = f2bs(xr.w + fmaxf(acc[mt][nt][3] + s.w + bo, 0.f));
            }
        }
    }
}

// ---------------------------------------------------------------------------
// Kernel 2 (fused, M=32/wave, TAP-SPLIT): conv2-MFMA partial -> LDS offset
// reduce -> bilinear gather (own taps) -> deform MFMA partial -> LDS acc
// reduce -> out.  Block = 64 px, 4 waves = 2 pairs; tg splits taps 0-3/4-8.
// 1024 blocks -> 4 blocks/CU, 4 waves/SIMD, VGPR cap 128 (round-0 natural).
// ---------------------------------------------------------------------------
__global__ __launch_bounds__(256, 4) void k_deform(const short* __restrict__ x3b,
                                                   const short* __restrict__ wB2,
                                                   const float* __restrict__ off_b,
                                                   const short* __restrict__ wB,
                                                   const float* __restrict__ def_b,
                                                   float* __restrict__ out) {
    __shared__ float part[2][64][20];             // 10 KB conv2 partials
    __shared__ float4 accbuf[2][12][64];          // 24.5 KB acc exchange

    int pix0 = swizzle1024(blockIdx.x) * 64;
    int b = pix0 / HWD; int hw0 = pix0 % HWD;
    int h = hw0 / WD; int w0 = hw0 % WD;
    int tid = threadIdx.x;
    int l = tid & 63, wv = tid >> 6;
    int p = wv >> 1, tg = wv & 1;                 // pair, tap-group
    int q = l >> 4, mr = l & 15;
    int wq = 32*p;                                // pair's row base in block
    int t0 = tg ? 4 : 0, t1 = tg ? 9 : 4;
    const short* xb = x3b + ((size_t)b * HWD) * 96;
    const bfrag az = {0,0,0,0,0,0,0,0};

    // ---- conv2 via MFMA: partial offsets (own taps) for pair's 32 px ----
    ffrag oa[2][2];
    #pragma unroll
    for (int mt = 0; mt < 2; mt++)
        #pragma unroll
        for (int nt = 0; nt < 2; nt++) oa[mt][nt] = ffrag{0.f,0.f,0.f,0.f};

    #pragma unroll 1
    for (int tap = t0; tap < t1; tap++) {
        int y = h + tap/3 - 1;
        if ((unsigned)y >= HD) continue;
        const short* abase[2]; bool vx[2];
        #pragma unroll
        for (int mt = 0; mt < 2; mt++) {
            int xx = w0 + wq + 16*mt + mr + tap%3 - 1;
            int xxc = min(max(xx, 0), WD-1);
            vx[mt] = (unsigned)xx < WD;
            abase[mt] = xb + ((size_t)(y*WD + xxc))*96 + q*8;
        }
        #pragma unroll
        for (int sc = 0; sc < 3; sc++) {
            const short* wb = wB2 + ((size_t)((tap*3+sc)*2)*64 + l)*8;
            bfrag b0 = *(const bfrag*)(wb);
            bfrag b1 = *(const bfrag*)(wb + 512);
            #pragma unroll
            for (int mt = 0; mt < 2; mt++) {
                bfrag a = *(const bfrag*)(abase[mt] + sc*32);
                if (!vx[mt]) a = az;
                oa[mt][0] = __builtin_amdgcn_mfma_f32_16x16x32_bf16(a, b0, oa[mt][0], 0, 0, 0);
                oa[mt][1] = __builtin_amdgcn_mfma_f32_16x16x32_bf16(a, b1, oa[mt][1], 0, 0, 0);
            }
        }
    }
    // write partials (bias folded into tg=0's plane)
    #pragma unroll
    for (int mt = 0; mt < 2; mt++) {
        int row = wq + 16*mt + q*4;
        float bo0 = tg ? 0.f : off_b[mr];
        #pragma unroll
        for (int r = 0; r < 4; r++) part[tg][row + r][mr] = oa[mt][0][r] + bo0;
        if (mr < 2) {
            float bo1 = tg ? 0.f : off_b[16 + mr];
            #pragma unroll
            for (int r = 0; r < 4; r++) part[tg][row + r][16 + mr] = oa[mt][1][r] + bo1;
        }
    }
    __syncthreads();

    // ---- gather + deform MFMA (own taps) ----
    ffrag acc[2][6];
    #pragma unroll
    for (int mt = 0; mt < 2; mt++)
        #pragma unroll
        for (int nt = 0; nt < 6; nt++) acc[mt][nt] = ffrag{0.f,0.f,0.f,0.f};

    #pragma unroll 1
    for (int tap = t0; tap < t1; tap++) {
        const short* pp[2][4];
        float fb[2][4];
        #pragma unroll
        for (int mt = 0; mt < 2; mt++) {
            int lp = wq + 16*mt + mr;          // local pixel row in part
            int w = w0 + lp;                   // global x coordinate
            float dy = part[0][lp][2*tap]     + part[1][lp][2*tap];
            float dx = part[0][lp][2*tap + 1] + part[1][lp][2*tap + 1];
            float py  = (float)(h + tap/3 - 1) + dy;
            float pxf = (float)(w + tap%3 - 1) + dx;
            float y0f = floorf(py), x0f = floorf(pxf);
            float wy = py - y0f, wx = pxf - x0f;
            int y0 = (int)y0f, x0 = (int)x0f;
            int y1 = y0 + 1, x1 = x0 + 1;
            bool vy0 = (unsigned)y0 < HD, vy1 = (unsigned)y1 < HD;
            bool vx0 = (unsigned)x0 < WD, vx1 = (unsigned)x1 < WD;
            fb[mt][0] = (vy0 && vx0) ? (1.f-wy)*(1.f-wx) : 0.f;
            fb[mt][1] = (vy0 && vx1) ? (1.f-wy)*wx       : 0.f;
            fb[mt][2] = (vy1 && vx0) ? wy*(1.f-wx)       : 0.f;
            fb[mt][3] = (vy1 && vx1) ? wy*wx             : 0.f;
            int yc0 = min(max(y0,0),HD-1), yc1 = min(max(y1,0),HD-1);
            int xc0 = min(max(x0,0),WD-1), xc1 = min(max(x1,0),WD-1);
            pp[mt][0] = xb + ((size_t)(yc0*WD + xc0))*96 + q*8;
            pp[mt][1] = xb + ((size_t)(yc0*WD + xc1))*96 + q*8;
            pp[mt][2] = xb + ((size_t)(yc1*WD + xc0))*96 + q*8;
            pp[mt][3] = xb + ((size_t)(yc1*WD + xc1))*96 + q*8;
        }
        #pragma unroll
        for (int sc = 0; sc < 3; sc++) {
            int s = tap*3 + sc;
            const short* wb = wB + ((size_t)(s*6)*64 + l)*8;
            bfrag bbf[6];
            #pragma unroll
            for (int nt = 0; nt < 6; nt++) bbf[nt] = *(const bfrag*)(wb + nt*512);
            #pragma unroll
            for (int mt = 0; mt < 2; mt++) {
                bfrag c00 = *(const bfrag*)(pp[mt][0] + sc*32);
                bfrag c01 = *(const bfrag*)(pp[mt][1] + sc*32);
                bfrag c10 = *(const bfrag*)(pp[mt][2] + sc*32);
                bfrag c11 = *(const bfrag*)(pp[mt][3] + sc*32);
                const int* i00 = (const int*)&c00;
                const int* i01 = (const int*)&c01;
                const int* i10 = (const int*)&c10;
                const int* i11 = (const int*)&c11;
                float f00 = fb[mt][0], f01 = fb[mt][1];
                float f10 = fb[mt][2], f11 = fb[mt][3];
                int ap[4];
                #pragma unroll
                for (int d = 0; d < 4; d++) {
                    float a0 = __int_as_float(((unsigned)i00[d]) << 16);
                    float b0f = __int_as_float(((unsigned)i01[d]) << 16);
                    float c0f = __int_as_float(((unsigned)i10[d]) << 16);
                    float d0 = __int_as_float(((unsigned)i11[d]) << 16);
                    float a1 = __int_as_float(i00[d] & 0xffff0000);
                    float b1f = __int_as_float(i01[d] & 0xffff0000);
                    float c1f = __int_as_float(i10[d] & 0xffff0000);
                    float d1 = __int_as_float(i11[d] & 0xffff0000);
                    float rlo = f00*a0 + f01*b0f + f10*c0f + f11*d0;
                    float rhi = f00*a1 + f01*b1f + f10*c1f + f11*d1;
                    ap[d] = (int)((unsigned short)f2bs(rlo)) |
                            ((int)((unsigned short)f2bs(rhi)) << 16);
                }
                bfrag a = *(const bfrag*)ap;
                #pragma unroll
                for (int nt = 0; nt < 6; nt++)
                    acc[mt][nt] = __builtin_amdgcn_mfma_f32_16x16x32_bf16(a, bbf[nt], acc[mt][nt], 0, 0, 0);
            }
        }
    }

    // ---- pair-reduce acc and epilogue (tg=0 stores) ----
    if (tg) {
        #pragma unroll
        for (int mt = 0; mt < 2; mt++)
            #pragma unroll
            for (int nt = 0; nt < 6; nt++)
                accbuf[p][mt*6+nt][l] = float4{acc[mt][nt][0], acc[mt][nt][1],
                                               acc[mt][nt][2], acc[mt][nt][3]};
    }
    __syncthreads();
    if (!tg) {
        #pragma unroll
        for (int mt = 0; mt < 2; mt++) {
            int hwb = hw0 + wq + 16*mt + q*4;
            #pragma unroll
            for (int nt = 0; nt < 6; nt++) {
                float4 s = accbuf[p][mt*6+nt][l];
                int o = 16*nt + mr;
                float bo = def_b[o];
                float4 v;
                v.x = acc[mt][nt][0] + s.x + bo; v.y = acc[mt][nt][1] + s.y + bo;
                v.z = acc[mt][nt][2] + s.z + bo; v.w = acc[mt][nt][3] + s.w + bo;
                *(float4*)(out + ((size_t)(b*96 + o))*HWD + hwb) = v;
            }
        }
    }
}

// ---------------------------------------------------------------------------
// Workspace layout (bytes):
//   xb16 : 0        .. 12582912   (B*HW*96 bf16, NHWC of x)
//   x3b  : 12582912 .. 25165824   (B*HW*96 bf16, NHWC of x3)
//   wB1  : 25165824 .. 25331712
//   wB2  : 25331712 .. 25387008
//   wB   : 25387008 .. 25552896
// ---------------------------------------------------------------------------
extern "C" void kernel_launch(void* const* d_in, const int* in_sizes, int n_in,
                              void* d_out, int out_size, void* d_ws, size_t ws_size,
                              hipStream_t stream) {
    const float* x       = (const float*)d_in[0];
    const float* dconv_w = (const float*)d_in[1];
    const float* dconv_b = (const float*)d_in[2];
    const float* off_w   = (const float*)d_in[3];
    const float* off_b   = (const float*)d_in[4];
    const float* def_w   = (const float*)d_in[5];
    const float* def_b   = (const float*)d_in[6];
    float* out = (float*)d_out;

    char* ws = (char*)d_ws;
    short* xb16 = (short*)(ws);
    short* x3b  = (short*)(ws + 12582912);
    short* wB1  = (short*)(ws + 25165824);
    short* wB2  = (short*)(ws + 25331712);
    short* wB   = (short*)(ws + 25387008);

    k_repack<<<324, 256, 0, stream>>>(dconv_w, off_w, def_w, wB1, wB2, wB);
    k_transpose<<<(BD*HWD)/128, 256, 0, stream>>>(x, xb16);
    k_conv1<<<(BD*HWD)/64, 256, 0, stream>>>(x, xb16, wB1, dconv_b, x3b);
    k_deform<<<(BD*HWD)/64, 256, 0, stream>>>(x3b, wB2, off_b, wB, def_b, out);
}

// Round 5
// 175.952 us; speedup vs baseline: 1.6017x; 1.5491x over previous
//
#include <hip/hip_runtime.h>
#include <hip/hip_bf16.h>

#define BD 4
#define CD 96
#define OD 96
#define HD 128
#define WD 128
#define HWD (HD*WD)          // 16384

typedef __attribute__((ext_vector_type(8))) short bfrag;   // 8 bf16 (4 VGPRs)
typedef __attribute__((ext_vector_type(4))) float ffrag;   // 4 fp32 acc

__device__ __forceinline__ short f2bs(float f) {
    __hip_bfloat16 h = __float2bfloat16(f);
    return *reinterpret_cast<short*>(&h);
}

// XCD-aware swizzles (round-robin dispatch over 8 XCDs): XCD k owns a
// contiguous chunk of logical blocks -> consecutive image rows -> halos in L2.
__device__ __forceinline__ int swizzle1024(int gid) {
    return ((gid & 7) << 7) | (gid >> 3);
}
__device__ __forceinline__ int swizzle2048(int gid) {
    return ((gid & 7) << 8) | (gid >> 3);
}

// ---------------------------------------------------------------------------
// Transpose: x (NCHW fp32) -> xb16 (pixel-major NHWC bf16). 64 px/block,
// 1024 blocks (13 KB LDS) for 4 blocks/CU.
// ---------------------------------------------------------------------------
__global__ __launch_bounds__(256) void k_transpose(const float* __restrict__ x,
                                                   short* __restrict__ xb16) {
    __shared__ short tile[64 * 104];
    int pix0 = blockIdx.x * 64;
    int b = pix0 / HWD; int hw0 = pix0 % HWD;
    int tid = threadIdx.x;

    for (int e = tid; e < 96*16; e += 256) {
        int c = e >> 4, g = e & 15;
        float4 v = *(const float4*)(x + ((size_t)(b*96 + c))*HWD + hw0 + 4*g);
        tile[(4*g+0)*104 + c] = f2bs(v.x);
        tile[(4*g+1)*104 + c] = f2bs(v.y);
        tile[(4*g+2)*104 + c] = f2bs(v.z);
        tile[(4*g+3)*104 + c] = f2bs(v.w);
    }
    __syncthreads();
    for (int e = tid; e < 64*12; e += 256) {
        int px = e / 12, c8 = e % 12;
        bfrag v = *(const bfrag*)(tile + px*104 + c8*8);
        *(bfrag*)(xb16 + ((size_t)(pix0 + px))*96 + c8*8) = v;
    }
}

// ---------------------------------------------------------------------------
// Repack weights to bf16 MFMA B-frag layouts (k = tap*96 + c):
//   wB1 (864x96): dconv_w   wB2 (864x32, o<18): off_w   wB (864x96): def_w
//   order: w[((s*NT+nt)*64 + l)*8 + j] = B[k=32s+(l>>4)*8+j][o=16nt+(l&15)]
// ---------------------------------------------------------------------------
__global__ void k_repack(const float* __restrict__ dconv_w,
                         const float* __restrict__ off_w,
                         const float* __restrict__ def_w,
                         short* __restrict__ wB1,
                         short* __restrict__ wB2,
                         short* __restrict__ wB) {
    int t = blockIdx.x * blockDim.x + threadIdx.x;
    if (t < 27648) {              // 864 x 32, NT=2
        int j = t & 7; int l = (t >> 3) & 63; int tile = t >> 9;
        int s = tile >> 1, nt = tile & 1;
        int k = 32*s + (l >> 4)*8 + j;
        int o = 16*nt + (l & 15);
        int c = k % 96, tap = k / 96;
        wB2[t] = (o < 18) ? f2bs(off_w[(o*96 + c)*9 + tap]) : (short)0;
    }
    if (t < 82944) {              // 864 x 96, NT=6
        int j = t & 7; int l = (t >> 3) & 63; int tile = t >> 9;
        int s = tile / 6, nt = tile % 6;
        int k = 32*s + (l >> 4)*8 + j;
        int o = 16*nt + (l & 15);
        int c = k % 96, tap = k / 96;
        wB1[t] = f2bs(dconv_w[(o*96 + c)*9 + tap]);
        wB[t]  = f2bs(def_w [(o*96 + c)*9 + tap]);
    }
}

// ---------------------------------------------------------------------------
// Kernel 1 (N-SPLIT): x3b = bf16(x + relu(conv3x3 dil2 pad2(x))), NHWC.
// Block = 64 px, 4 waves = 2 pixel-halves x 2 n-halves. Each wave: 32 px
// (two 16-px m-tiles, A-frag reuse) x 3 of 6 n-tiles (acc 24 AGPR).
// A-loads duplicated across the n-pair (same addresses -> L1 hit).
// 1024 blocks x 4 waves = 4096 waves -> 16 waves/CU = 4 waves/SIMD.
// ---------------------------------------------------------------------------
__global__ __launch_bounds__(256, 3) void k_conv1(const float* __restrict__ x,
                                                  const short* __restrict__ xb16,
                                                  const short* __restrict__ wB,
                                                  const float* __restrict__ bias,
                                                  short* __restrict__ x3b) {
    int pix0 = swizzle1024(blockIdx.x) * 64;
    int b = pix0 / HWD; int hw0 = pix0 % HWD;
    int h = hw0 / WD; int w0 = hw0 % WD;
    int tid = threadIdx.x;
    int l = tid & 63, wv = tid >> 6;
    int pr = wv >> 1, tg = wv & 1;            // pixel-half, n-half
    int q = l >> 4, mr = l & 15;
    int wq = w0 + 32*pr;
    const char* xbc = (const char*)(xb16 + ((size_t)b * HWD) * 96);
    const bfrag az = {0,0,0,0,0,0,0,0};

    ffrag acc[2][3];
    #pragma unroll
    for (int mt = 0; mt < 2; mt++)
        #pragma unroll
        for (int n = 0; n < 3; n++) acc[mt][n] = ffrag{0.f,0.f,0.f,0.f};

    #pragma unroll 1
    for (int tap = 0; tap < 9; tap++) {
        int y = h + (tap/3)*2 - 2;
        if ((unsigned)y >= HD) continue;
        unsigned aoff[2]; bool vx[2];
        #pragma unroll
        for (int mt = 0; mt < 2; mt++) {
            int xx = wq + 16*mt + mr + (tap%3)*2 - 2;
            int xxc = min(max(xx, 0), WD-1);
            vx[mt] = (unsigned)xx < WD;
            aoff[mt] = (unsigned)(((y*WD + xxc)*96 + q*8) * 2);
        }
        #pragma unroll
        for (int sc = 0; sc < 3; sc++) {
            const short* wb = wB + ((size_t)((tap*3+sc)*6 + 3*tg)*64 + l)*8;
            bfrag bb[3];
            #pragma unroll
            for (int n = 0; n < 3; n++) bb[n] = *(const bfrag*)(wb + n*512);
            #pragma unroll
            for (int mt = 0; mt < 2; mt++) {
                bfrag a = *(const bfrag*)(xbc + aoff[mt] + sc*64);
                if (!vx[mt]) a = az;
                #pragma unroll
                for (int n = 0; n < 3; n++)
                    acc[mt][n] = __builtin_amdgcn_mfma_f32_16x16x32_bf16(a, bb[n], acc[mt][n], 0, 0, 0);
            }
        }
    }

    #pragma unroll
    for (int mt = 0; mt < 2; mt++) {
        int hwb = hw0 + 32*pr + 16*mt + q*4;
        #pragma unroll
        for (int n = 0; n < 3; n++) {
            int o = 16*(3*tg + n) + mr;
            float bo = bias[o];
            float4 xr = *(const float4*)(x + ((size_t)(b*96 + o))*HWD + hwb);
            short* op = x3b + ((size_t)(b*HWD + hwb))*96 + o;
            op[0]   = f2bs(xr.x + fmaxf(acc[mt][n][0] + bo, 0.f));
            op[96]  = f2bs(xr.y + fmaxf(acc[mt][n][1] + bo, 0.f));
            op[192] = f2bs(xr.z + fmaxf(acc[mt][n][2] + bo, 0.f));
            op[288] = f2bs(xr.w + fmaxf(acc[mt][n][3] + bo, 0.f));
        }
    }
}

// ---------------------------------------------------------------------------
// Kernel 2 (fused, N-SPLIT pair): block = 1 pair (2 waves, 128 thr) owning
// 32 px. Wave tg: conv2-MFMA offsets for its 16 px (no barrier, same-wave
// produce/consume via offsb) -> gather+interp its 16 px -> publish bf16
// A-rows to LDS (double-buffered, 1 barrier/tap) -> both waves MFMA BOTH
// m-tiles x their own 3 n-tiles.  Per-pixel VMEM = round-0 level; waves
// double to 4096 -> 16 waves/CU = 4 waves/SIMD; ~125 total regs (no spill).
// Barrier safety: both waves execute exactly 9 barriers (no divergent exit
// crosses one); tap-t reads of abuf[buf] drain before the tap-t+1 barrier,
// so 2 buffers + 1 barrier/tap cannot race.
// ---------------------------------------------------------------------------
__global__ __launch_bounds__(128, 3) void k_deform(const short* __restrict__ x3b,
                                                   const short* __restrict__ wB2,
                                                   const float* __restrict__ off_b,
                                                   const short* __restrict__ wB,
                                                   const float* __restrict__ def_b,
                                                   float* __restrict__ out) {
    __shared__ float offsb[32][20];               // 2.5 KB per-pixel offsets
    __shared__ short abuf[2][2][3][512];          // 12 KB A-frag exchange [buf][mt][sc][l*8]

    int pix0 = swizzle2048(blockIdx.x) * 32;
    int b = pix0 / HWD; int hw0 = pix0 % HWD;
    int h = hw0 / WD; int w0 = hw0 % WD;
    int tid = threadIdx.x;
    int l = tid & 63, tg = tid >> 6;              // tg in {0,1}: m-tile & n-half
    int q = l >> 4, mr = l & 15;
    const short* xb = x3b + ((size_t)b * HWD) * 96;
    const char* xbc = (const char*)xb;
    const bfrag az = {0,0,0,0,0,0,0,0};

    // ---- conv2 via MFMA: offsets for this wave's own 16 px (m-tile tg) ----
    ffrag oa[2];
    oa[0] = ffrag{0.f,0.f,0.f,0.f};
    oa[1] = ffrag{0.f,0.f,0.f,0.f};

    #pragma unroll 1
    for (int tap = 0; tap < 9; tap++) {
        int y = h + tap/3 - 1;
        if ((unsigned)y >= HD) continue;
        int xx = w0 + 16*tg + mr + tap%3 - 1;
        int xxc = min(max(xx, 0), WD-1);
        bool vx = (unsigned)xx < WD;
        unsigned aoff = (unsigned)(((y*WD + xxc)*96 + q*8) * 2);
        #pragma unroll
        for (int sc = 0; sc < 3; sc++) {
            const short* wb = wB2 + ((size_t)((tap*3+sc)*2)*64 + l)*8;
            bfrag b0 = *(const bfrag*)(wb);
            bfrag b1 = *(const bfrag*)(wb + 512);
            bfrag a = *(const bfrag*)(xbc + aoff + sc*64);
            if (!vx) a = az;
            oa[0] = __builtin_amdgcn_mfma_f32_16x16x32_bf16(a, b0, oa[0], 0, 0, 0);
            oa[1] = __builtin_amdgcn_mfma_f32_16x16x32_bf16(a, b1, oa[1], 0, 0, 0);
        }
    }
    {
        int row = 16*tg + q*4;
        float bo0 = off_b[mr];
        #pragma unroll
        for (int r = 0; r < 4; r++) offsb[row + r][mr] = oa[0][r] + bo0;
        if (mr < 2) {
            float bo1 = off_b[16 + mr];
            #pragma unroll
            for (int r = 0; r < 4; r++) offsb[row + r][16 + mr] = oa[1][r] + bo1;
        }
    }
    // no barrier: offsb rows 16*tg..16*tg+15 produced & consumed by wave tg

    // ---- gather (own 16 px) -> LDS A-frags -> MFMA both m-tiles, own 3 nt ----
    ffrag acc[2][3];
    #pragma unroll
    for (int mt = 0; mt < 2; mt++)
        #pragma unroll
        for (int n = 0; n < 3; n++) acc[mt][n] = ffrag{0.f,0.f,0.f,0.f};

    int buf = 0;
    #pragma unroll 1
    for (int tap = 0; tap < 9; tap++) {
        unsigned po[4];
        float fb[4];
        {
            int lp = 16*tg + mr;               // own pixel row
            int w = w0 + lp;
            float dy = offsb[lp][2*tap];
            float dx = offsb[lp][2*tap + 1];
            float py  = (float)(h + tap/3 - 1) + dy;
            float pxf = (float)(w + tap%3 - 1) + dx;
            float y0f = floorf(py), x0f = floorf(pxf);
            float wy = py - y0f, wx = pxf - x0f;
            int y0 = (int)y0f, x0 = (int)x0f;
            int y1 = y0 + 1, x1 = x0 + 1;
            bool vy0 = (unsigned)y0 < HD, vy1 = (unsigned)y1 < HD;
            bool vx0 = (unsigned)x0 < WD, vx1 = (unsigned)x1 < WD;
            fb[0] = (vy0 && vx0) ? (1.f-wy)*(1.f-wx) : 0.f;
            fb[1] = (vy0 && vx1) ? (1.f-wy)*wx       : 0.f;
            fb[2] = (vy1 && vx0) ? wy*(1.f-wx)       : 0.f;
            fb[3] = (vy1 && vx1) ? wy*wx             : 0.f;
            int yc0 = min(max(y0,0),HD-1), yc1 = min(max(y1,0),HD-1);
            int xc0 = min(max(x0,0),WD-1), xc1 = min(max(x1,0),WD-1);
            po[0] = (unsigned)(((yc0*WD + xc0)*96 + q*8)*2);
            po[1] = (unsigned)(((yc0*WD + xc1)*96 + q*8)*2);
            po[2] = (unsigned)(((yc1*WD + xc0)*96 + q*8)*2);
            po[3] = (unsigned)(((yc1*WD + xc1)*96 + q*8)*2);
        }
        // gather + interp own pixels, publish A-rows
        #pragma unroll
        for (int sc = 0; sc < 3; sc++) {
            bfrag c00 = *(const bfrag*)(xbc + po[0] + sc*64);
            bfrag c01 = *(const bfrag*)(xbc + po[1] + sc*64);
            bfrag c10 = *(const bfrag*)(xbc + po[2] + sc*64);
            bfrag c11 = *(const bfrag*)(xbc + po[3] + sc*64);
            const int* i00 = (const int*)&c00;
            const int* i01 = (const int*)&c01;
            const int* i10 = (const int*)&c10;
            const int* i11 = (const int*)&c11;
            float f00 = fb[0], f01 = fb[1], f10 = fb[2], f11 = fb[3];
            int ap[4];
            #pragma unroll
            for (int d = 0; d < 4; d++) {
                float a0 = __int_as_float(((unsigned)i00[d]) << 16);
                float b0f = __int_as_float(((unsigned)i01[d]) << 16);
                float c0f = __int_as_float(((unsigned)i10[d]) << 16);
                float d0 = __int_as_float(((unsigned)i11[d]) << 16);
                float a1 = __int_as_float(i00[d] & 0xffff0000);
                float b1f = __int_as_float(i01[d] & 0xffff0000);
                float c1f = __int_as_float(i10[d] & 0xffff0000);
                float d1 = __int_as_float(i11[d] & 0xffff0000);
                float rlo = f00*a0 + f01*b0f + f10*c0f + f11*d0;
                float rhi = f00*a1 + f01*b1f + f10*c1f + f11*d1;
                ap[d] = (int)((unsigned short)f2bs(rlo)) |
                        ((int)((unsigned short)f2bs(rhi)) << 16);
            }
            *(bfrag*)&abuf[buf][tg][sc][l*8] = *(const bfrag*)ap;
        }
        __syncthreads();   // A-rows of both m-tiles visible; skew bounded to 1 tap
        #pragma unroll
        for (int sc = 0; sc < 3; sc++) {
            const short* wb = wB + ((size_t)((tap*3+sc)*6 + 3*tg)*64 + l)*8;
            bfrag bb[3];
            #pragma unroll
            for (int n = 0; n < 3; n++) bb[n] = *(const bfrag*)(wb + n*512);
            bfrag a0 = *(const bfrag*)&abuf[buf][0][sc][l*8];
            bfrag a1 = *(const bfrag*)&abuf[buf][1][sc][l*8];
            #pragma unroll
            for (int n = 0; n < 3; n++) {
                acc[0][n] = __builtin_amdgcn_mfma_f32_16x16x32_bf16(a0, bb[n], acc[0][n], 0, 0, 0);
                acc[1][n] = __builtin_amdgcn_mfma_f32_16x16x32_bf16(a1, bb[n], acc[1][n], 0, 0, 0);
            }
        }
        buf ^= 1;
    }

    // ---- epilogue: NCHW fp32 out; wave writes both m-tiles x its 3 nt ----
    #pragma unroll
    for (int mt = 0; mt < 2; mt++) {
        int hwb = hw0 + 16*mt + q*4;
        #pragma unroll
        for (int n = 0; n < 3; n++) {
            int o = 16*(3*tg + n) + mr;
            float bo = def_b[o];
            float4 v;
            v.x = acc[mt][n][0] + bo; v.y = acc[mt][n][1] + bo;
            v.z = acc[mt][n][2] + bo; v.w = acc[mt][n][3] + bo;
            *(float4*)(out + ((size_t)(b*96 + o))*HWD + hwb) = v;
        }
    }
}

// ---------------------------------------------------------------------------
// Workspace layout (bytes):
//   xb16 : 0        .. 12582912   (B*HW*96 bf16, NHWC of x)
//   x3b  : 12582912 .. 25165824   (B*HW*96 bf16, NHWC of x3)
//   wB1  : 25165824 .. 25331712
//   wB2  : 25331712 .. 25387008
//   wB   : 25387008 .. 25552896
// ---------------------------------------------------------------------------
extern "C" void kernel_launch(void* const* d_in, const int* in_sizes, int n_in,
                              void* d_out, int out_size, void* d_ws, size_t ws_size,
                              hipStream_t stream) {
    const float* x       = (const float*)d_in[0];
    const float* dconv_w = (const float*)d_in[1];
    const float* dconv_b = (const float*)d_in[2];
    const float* off_w   = (const float*)d_in[3];
    const float* off_b   = (const float*)d_in[4];
    const float* def_w   = (const float*)d_in[5];
    const float* def_b   = (const float*)d_in[6];
    float* out = (float*)d_out;

    char* ws = (char*)d_ws;
    short* xb16 = (short*)(ws);
    short* x3b  = (short*)(ws + 12582912);
    short* wB1  = (short*)(ws + 25165824);
    short* wB2  = (short*)(ws + 25331712);
    short* wB   = (short*)(ws + 25387008);

    k_repack<<<324, 256, 0, stream>>>(dconv_w, off_w, def_w, wB1, wB2, wB);
    k_transpose<<<(BD*HWD)/64, 256, 0, stream>>>(x, xb16);
    k_conv1<<<(BD*HWD)/64, 256, 0, stream>>>(x, xb16, wB1, dconv_b, x3b);
    k_deform<<<(BD*HWD)/32, 128, 0, stream>>>(x3b, wB2, off_b, wB, def_b, out);
}

// Round 6
// 162.269 us; speedup vs baseline: 1.7368x; 1.0843x over previous
//
#include <hip/hip_runtime.h>
#include <hip/hip_bf16.h>

#define BD 4
#define CD 96
#define OD 96
#define HD 128
#define WD 128
#define HWD (HD*WD)          // 16384

typedef __attribute__((ext_vector_type(8))) short bfrag;   // 8 bf16 (4 VGPRs)
typedef __attribute__((ext_vector_type(4))) float ffrag;   // 4 fp32 acc

__device__ __forceinline__ short f2bs(float f) {
    __hip_bfloat16 h = __float2bfloat16(f);
    return *reinterpret_cast<short*>(&h);
}

// XCD-aware swizzles. 256-block grids: XCD k owns 32 consecutive logical
// blocks = half an image (64 rows) -> tap/gather halos stay in its L2.
__device__ __forceinline__ int swizzle256(int gid) {
    return ((gid & 7) << 5) | (gid >> 3);
}

// ---------------------------------------------------------------------------
// Transpose: x (NCHW fp32) -> xb16 (pixel-major NHWC bf16). 64 px/block.
// ---------------------------------------------------------------------------
__global__ __launch_bounds__(256) void k_transpose(const float* __restrict__ x,
                                                   short* __restrict__ xb16) {
    __shared__ short tile[64 * 104];
    int pix0 = blockIdx.x * 64;
    int b = pix0 / HWD; int hw0 = pix0 % HWD;
    int tid = threadIdx.x;

    for (int e = tid; e < 96*16; e += 256) {
        int c = e >> 4, g = e & 15;
        float4 v = *(const float4*)(x + ((size_t)(b*96 + c))*HWD + hw0 + 4*g);
        tile[(4*g+0)*104 + c] = f2bs(v.x);
        tile[(4*g+1)*104 + c] = f2bs(v.y);
        tile[(4*g+2)*104 + c] = f2bs(v.z);
        tile[(4*g+3)*104 + c] = f2bs(v.w);
    }
    __syncthreads();
    for (int e = tid; e < 64*12; e += 256) {
        int px = e / 12, c8 = e % 12;
        bfrag v = *(const bfrag*)(tile + px*104 + c8*8);
        *(bfrag*)(xb16 + ((size_t)(pix0 + px))*96 + c8*8) = v;
    }
}

// ---------------------------------------------------------------------------
// Repack weights to bf16 MFMA B-frag layouts (k = tap*96 + c):
//   wB1 (864x96): dconv_w   wB2 (864x32, o<18): off_w   wB (864x96): def_w
//   order: w[((s*NT+nt)*64 + l)*8 + j] = B[k=32s+(l>>4)*8+j][o=16nt+(l&15)]
// ---------------------------------------------------------------------------
__global__ void k_repack(const float* __restrict__ dconv_w,
                         const float* __restrict__ off_w,
                         const float* __restrict__ def_w,
                         short* __restrict__ wB1,
                         short* __restrict__ wB2,
                         short* __restrict__ wB) {
    int t = blockIdx.x * blockDim.x + threadIdx.x;
    if (t < 27648) {              // 864 x 32, NT=2
        int j = t & 7; int l = (t >> 3) & 63; int tile = t >> 9;
        int s = tile >> 1, nt = tile & 1;
        int k = 32*s + (l >> 4)*8 + j;
        int o = 16*nt + (l & 15);
        int c = k % 96, tap = k / 96;
        wB2[t] = (o < 18) ? f2bs(off_w[(o*96 + c)*9 + tap]) : (short)0;
    }
    if (t < 82944) {              // 864 x 96, NT=6
        int j = t & 7; int l = (t >> 3) & 63; int tile = t >> 9;
        int s = tile / 6, nt = tile % 6;
        int k = 32*s + (l >> 4)*8 + j;
        int o = 16*nt + (l & 15);
        int c = k % 96, tap = k / 96;
        wB1[t] = f2bs(dconv_w[(o*96 + c)*9 + tap]);
        wB[t]  = f2bs(def_w [(o*96 + c)*9 + tap]);
    }
}

// ---------------------------------------------------------------------------
// Weight staging helpers: one 18 KB tap-slice (3 sc x 6 nt x 1 KB) is moved
// global->regs->LDS by the whole 512-thread block (1152 16B chunks, 3 rounds).
// Loads issued early (tap top), ds_write late (tap bottom) -> T14 overlap.
// ---------------------------------------------------------------------------
#define SLICE_SHORTS 9216      // 18 KB per tap slice

// ---------------------------------------------------------------------------
// Kernel 1 (M=32/wave, LDS weights): x3b = bf16(x + relu(conv3x3 dil2 pad2)).
// Block = 512 thr (8 waves), 256 px; wave owns 32 px (two 16-px m-tiles,
// B-frags shared) x all 6 n-tiles. Weight slices double-buffered in LDS:
// weight reads leave the TA path (81 -> ~10 lines/px).  Grid 256 = 1 blk/CU.
// ---------------------------------------------------------------------------
__global__ __launch_bounds__(512, 2) void k_conv1(const float* __restrict__ x,
                                                  const short* __restrict__ xb16,
                                                  const short* __restrict__ wB,
                                                  const float* __restrict__ bias,
                                                  short* __restrict__ x3b) {
    __shared__ short wbuf[2][SLICE_SHORTS];       // 36 KB

    int pix0 = swizzle256(blockIdx.x) * 256;
    int b = pix0 / HWD; int hw0 = pix0 % HWD;
    int h0 = hw0 / WD;                            // block = 2 image rows
    int tid = threadIdx.x;
    int l = tid & 63, wv = tid >> 6;
    int q = l >> 4, mr = l & 15;
    const char* xbc = (const char*)(xb16 + ((size_t)b * HWD) * 96);
    const bfrag az = {0,0,0,0,0,0,0,0};

    // per-m-tile row / column bases (m-tiles never straddle a row: 16 | 128)
    int lpb[2], yb[2], wbx[2];
    #pragma unroll
    for (int mt = 0; mt < 2; mt++) {
        lpb[mt] = 32*wv + 16*mt;
        yb[mt]  = h0 + (lpb[mt] >> 7);
        wbx[mt] = (lpb[mt] & 127) + mr;
    }

    // prologue: stage slice 0
    {
        bfrag s0, s1, s2;
        int c0 = tid, c1 = tid + 512, c2 = tid + 1024;
        s0 = *(const bfrag*)(wB + c0*8);
        s1 = *(const bfrag*)(wB + c1*8);
        if (c2 < 1152) s2 = *(const bfrag*)(wB + c2*8);
        *(bfrag*)&wbuf[0][c0*8] = s0;
        *(bfrag*)&wbuf[0][c1*8] = s1;
        if (c2 < 1152) *(bfrag*)&wbuf[0][c2*8] = s2;
    }
    __syncthreads();

    ffrag acc[2][6];
    #pragma unroll
    for (int mt = 0; mt < 2; mt++)
        #pragma unroll
        for (int nt = 0; nt < 6; nt++) acc[mt][nt] = ffrag{0.f,0.f,0.f,0.f};

    int cur = 0;
    #pragma unroll 1
    for (int tap = 0; tap < 9; tap++) {
        // issue next slice loads early
        bfrag s0, s1, s2;
        if (tap < 8) {
            const short* src = wB + (size_t)(tap+1)*SLICE_SHORTS;
            int c2 = tid + 1024;
            s0 = *(const bfrag*)(src + tid*8);
            s1 = *(const bfrag*)(src + (tid+512)*8);
            if (c2 < 1152) s2 = *(const bfrag*)(src + c2*8);
        }

        int ty = (tap/3)*2 - 2, tx = (tap%3)*2 - 2;
        #pragma unroll
        for (int mt = 0; mt < 2; mt++) {
            int y = yb[mt] + ty;
            bool vy = (unsigned)y < HD;
            int yc = min(max(y, 0), HD-1);
            int xx = wbx[mt] + tx;
            int xxc = min(max(xx, 0), WD-1);
            bool v = vy && ((unsigned)xx < WD);
            unsigned aoff = (unsigned)(((yc*WD + xxc)*96 + q*8) * 2);
            #pragma unroll
            for (int sc = 0; sc < 3; sc++) {
                bfrag a = *(const bfrag*)(xbc + aoff + sc*64);
                if (!v) a = az;
                const short* wp = &wbuf[cur][(sc*6)*512 + l*8];
                #pragma unroll
                for (int nt = 0; nt < 6; nt++) {
                    bfrag bb = *(const bfrag*)(wp + nt*512);
                    acc[mt][nt] = __builtin_amdgcn_mfma_f32_16x16x32_bf16(a, bb, acc[mt][nt], 0, 0, 0);
                }
            }
        }

        if (tap < 8) {
            int c2 = tid + 1024;
            *(bfrag*)&wbuf[cur^1][tid*8]       = s0;
            *(bfrag*)&wbuf[cur^1][(tid+512)*8] = s1;
            if (c2 < 1152) *(bfrag*)&wbuf[cur^1][c2*8] = s2;
        }
        __syncthreads();
        cur ^= 1;
    }

    #pragma unroll
    for (int mt = 0; mt < 2; mt++) {
        int hwb = hw0 + lpb[mt] + q*4;
        #pragma unroll
        for (int nt = 0; nt < 6; nt++) {
            int o = 16*nt + mr;
            float bo = bias[o];
            float4 xr = *(const float4*)(x + ((size_t)(b*96 + o))*HWD + hwb);
            short* op = x3b + ((size_t)(b*HWD + hwb))*96 + o;
            op[0]   = f2bs(xr.x + fmaxf(acc[mt][nt][0] + bo, 0.f));
            op[96]  = f2bs(xr.y + fmaxf(acc[mt][nt][1] + bo, 0.f));
            op[192] = f2bs(xr.z + fmaxf(acc[mt][nt][2] + bo, 0.f));
            op[288] = f2bs(xr.w + fmaxf(acc[mt][nt][3] + bo, 0.f));
        }
    }
}

// ---------------------------------------------------------------------------
// Kernel 2 (fused, M=32/wave, LDS weights): conv2-MFMA (global B) -> offsb
// (own rows, no barrier) -> gather (TA floor: 108 lines/px) + deform MFMA
// with B from LDS tap-slices (double-buffered, 1 barrier/tap).
// Block = 512 thr (8 waves), 256 px, grid 256 = 1 blk/CU.
// ---------------------------------------------------------------------------
__global__ __launch_bounds__(512, 2) void k_deform(const short* __restrict__ x3b,
                                                   const short* __restrict__ wB2,
                                                   const float* __restrict__ off_b,
                                                   const short* __restrict__ wB,
                                                   const float* __restrict__ def_b,
                                                   float* __restrict__ out) {
    __shared__ short wbuf[2][SLICE_SHORTS];       // 36 KB
    __shared__ float offsb[256][20];              // 20 KB

    int pix0 = swizzle256(blockIdx.x) * 256;
    int b = pix0 / HWD; int hw0 = pix0 % HWD;
    int h0 = hw0 / WD;
    int tid = threadIdx.x;
    int l = tid & 63, wv = tid >> 6;
    int q = l >> 4, mr = l & 15;
    const char* xbc = (const char*)(x3b + ((size_t)b * HWD) * 96);
    const bfrag az = {0,0,0,0,0,0,0,0};

    int lpb[2], yb[2], wbx[2];
    #pragma unroll
    for (int mt = 0; mt < 2; mt++) {
        lpb[mt] = 32*wv + 16*mt;
        yb[mt]  = h0 + (lpb[mt] >> 7);
        wbx[mt] = (lpb[mt] & 127) + mr;
    }

    // prologue: stage deform slice 0
    {
        bfrag s0, s1, s2;
        int c2 = tid + 1024;
        s0 = *(const bfrag*)(wB + tid*8);
        s1 = *(const bfrag*)(wB + (tid+512)*8);
        if (c2 < 1152) s2 = *(const bfrag*)(wB + c2*8);
        *(bfrag*)&wbuf[0][tid*8]       = s0;
        *(bfrag*)&wbuf[0][(tid+512)*8] = s1;
        if (c2 < 1152) *(bfrag*)&wbuf[0][c2*8] = s2;
    }
    __syncthreads();

    // ---- conv2 via MFMA (B from global): offsets for this wave's 32 px ----
    ffrag oa[2][2];
    #pragma unroll
    for (int mt = 0; mt < 2; mt++)
        #pragma unroll
        for (int nt = 0; nt < 2; nt++) oa[mt][nt] = ffrag{0.f,0.f,0.f,0.f};

    #pragma unroll 1
    for (int tap = 0; tap < 9; tap++) {
        int ty = tap/3 - 1, tx = tap%3 - 1;
        #pragma unroll
        for (int mt = 0; mt < 2; mt++) {
            int y = yb[mt] + ty;
            bool vy = (unsigned)y < HD;
            int yc = min(max(y, 0), HD-1);
            int xx = wbx[mt] + tx;
            int xxc = min(max(xx, 0), WD-1);
            bool v = vy && ((unsigned)xx < WD);
            unsigned aoff = (unsigned)(((yc*WD + xxc)*96 + q*8) * 2);
            #pragma unroll
            for (int sc = 0; sc < 3; sc++) {
                const short* wb = wB2 + ((size_t)((tap*3+sc)*2)*64 + l)*8;
                bfrag b0 = *(const bfrag*)(wb);
                bfrag b1 = *(const bfrag*)(wb + 512);
                bfrag a = *(const bfrag*)(xbc + aoff + sc*64);
                if (!v) a = az;
                oa[mt][0] = __builtin_amdgcn_mfma_f32_16x16x32_bf16(a, b0, oa[mt][0], 0, 0, 0);
                oa[mt][1] = __builtin_amdgcn_mfma_f32_16x16x32_bf16(a, b1, oa[mt][1], 0, 0, 0);
            }
        }
    }
    #pragma unroll
    for (int mt = 0; mt < 2; mt++) {
        int row = lpb[mt] + q*4;
        float bo0 = off_b[mr];
        #pragma unroll
        for (int r = 0; r < 4; r++) offsb[row + r][mr] = oa[mt][0][r] + bo0;
        if (mr < 2) {
            float bo1 = off_b[16 + mr];
            #pragma unroll
            for (int r = 0; r < 4; r++) offsb[row + r][16 + mr] = oa[mt][1][r] + bo1;
        }
    }
    // no barrier: offsb rows 32wv..32wv+31 produced & consumed by wave wv

    // ---- gather + deform MFMA (B from LDS, dbuf slices) ----
    ffrag acc[2][6];
    #pragma unroll
    for (int mt = 0; mt < 2; mt++)
        #pragma unroll
        for (int nt = 0; nt < 6; nt++) acc[mt][nt] = ffrag{0.f,0.f,0.f,0.f};

    int cur = 0;
    #pragma unroll 1
    for (int tap = 0; tap < 9; tap++) {
        // issue next weight-slice loads early (hidden under gather+MFMA)
        bfrag s0, s1, s2;
        if (tap < 8) {
            const short* src = wB + (size_t)(tap+1)*SLICE_SHORTS;
            int c2 = tid + 1024;
            s0 = *(const bfrag*)(src + tid*8);
            s1 = *(const bfrag*)(src + (tid+512)*8);
            if (c2 < 1152) s2 = *(const bfrag*)(src + c2*8);
        }

        unsigned po[2][4];
        float fb[2][4];
        #pragma unroll
        for (int mt = 0; mt < 2; mt++) {
            int lp = lpb[mt] + mr;
            float dy = offsb[lp][2*tap];
            float dx = offsb[lp][2*tap + 1];
            float py  = (float)(yb[mt]  + tap/3 - 1) + dy;
            float pxf = (float)(wbx[mt] + tap%3 - 1) + dx;
            float y0f = floorf(py), x0f = floorf(pxf);
            float wy = py - y0f, wx = pxf - x0f;
            int y0 = (int)y0f, x0 = (int)x0f;
            int y1 = y0 + 1, x1 = x0 + 1;
            bool vy0 = (unsigned)y0 < HD, vy1 = (unsigned)y1 < HD;
            bool vx0 = (unsigned)x0 < WD, vx1 = (unsigned)x1 < WD;
            fb[mt][0] = (vy0 && vx0) ? (1.f-wy)*(1.f-wx) : 0.f;
            fb[mt][1] = (vy0 && vx1) ? (1.f-wy)*wx       : 0.f;
            fb[mt][2] = (vy1 && vx0) ? wy*(1.f-wx)       : 0.f;
            fb[mt][3] = (vy1 && vx1) ? wy*wx             : 0.f;
            int yc0 = min(max(y0,0),HD-1), yc1 = min(max(y1,0),HD-1);
            int xc0 = min(max(x0,0),WD-1), xc1 = min(max(x1,0),WD-1);
            po[mt][0] = (unsigned)(((yc0*WD + xc0)*96 + q*8)*2);
            po[mt][1] = (unsigned)(((yc0*WD + xc1)*96 + q*8)*2);
            po[mt][2] = (unsigned)(((yc1*WD + xc0)*96 + q*8)*2);
            po[mt][3] = (unsigned)(((yc1*WD + xc1)*96 + q*8)*2);
        }
        #pragma unroll
        for (int sc = 0; sc < 3; sc++) {
            const short* wp = &wbuf[cur][(sc*6)*512 + l*8];
            bfrag bbf[6];
            #pragma unroll
            for (int nt = 0; nt < 6; nt++) bbf[nt] = *(const bfrag*)(wp + nt*512);
            #pragma unroll
            for (int mt = 0; mt < 2; mt++) {
                bfrag c00 = *(const bfrag*)(xbc + po[mt][0] + sc*64);
                bfrag c01 = *(const bfrag*)(xbc + po[mt][1] + sc*64);
                bfrag c10 = *(const bfrag*)(xbc + po[mt][2] + sc*64);
                bfrag c11 = *(const bfrag*)(xbc + po[mt][3] + sc*64);
                const int* i00 = (const int*)&c00;
                const int* i01 = (const int*)&c01;
                const int* i10 = (const int*)&c10;
                const int* i11 = (const int*)&c11;
                float f00 = fb[mt][0], f01 = fb[mt][1];
                float f10 = fb[mt][2], f11 = fb[mt][3];
                int ap[4];
                #pragma unroll
                for (int d = 0; d < 4; d++) {
                    float a0 = __int_as_float(((unsigned)i00[d]) << 16);
                    float b0f = __int_as_float(((unsigned)i01[d]) << 16);
                    float c0f = __int_as_float(((unsigned)i10[d]) << 16);
                    float d0 = __int_as_float(((unsigned)i11[d]) << 16);
                    float a1 = __int_as_float(i00[d] & 0xffff0000);
                    float b1f = __int_as_float(i01[d] & 0xffff0000);
                    float c1f = __int_as_float(i10[d] & 0xffff0000);
                    float d1 = __int_as_float(i11[d] & 0xffff0000);
                    float rlo = f00*a0 + f01*b0f + f10*c0f + f11*d0;
                    float rhi = f00*a1 + f01*b1f + f10*c1f + f11*d1;
                    ap[d] = (int)((unsigned short)f2bs(rlo)) |
                            ((int)((unsigned short)f2bs(rhi)) << 16);
                }
                bfrag a = *(const bfrag*)ap;
                #pragma unroll
                for (int nt = 0; nt < 6; nt++)
                    acc[mt][nt] = __builtin_amdgcn_mfma_f32_16x16x32_bf16(a, bbf[nt], acc[mt][nt], 0, 0, 0);
            }
        }

        if (tap < 8) {
            int c2 = tid + 1024;
            *(bfrag*)&wbuf[cur^1][tid*8]       = s0;
            *(bfrag*)&wbuf[cur^1][(tid+512)*8] = s1;
            if (c2 < 1152) *(bfrag*)&wbuf[cur^1][c2*8] = s2;
        }
        __syncthreads();
        cur ^= 1;
    }

    // ---- epilogue: NCHW fp32 out, float4 per (m-tile, n-tile) ----
    #pragma unroll
    for (int mt = 0; mt < 2; mt++) {
        int hwb = hw0 + lpb[mt] + q*4;
        #pragma unroll
        for (int nt = 0; nt < 6; nt++) {
            int o = 16*nt + mr;
            float bo = def_b[o];
            float4 v;
            v.x = acc[mt][nt][0] + bo; v.y = acc[mt][nt][1] + bo;
            v.z = acc[mt][nt][2] + bo; v.w = acc[mt][nt][3] + bo;
            *(float4*)(out + ((size_t)(b*96 + o))*HWD + hwb) = v;
        }
    }
}

// ---------------------------------------------------------------------------
// Workspace layout (bytes):
//   xb16 : 0        .. 12582912   (B*HW*96 bf16, NHWC of x)
//   x3b  : 12582912 .. 25165824   (B*HW*96 bf16, NHWC of x3)
//   wB1  : 25165824 .. 25331712
//   wB2  : 25331712 .. 25387008
//   wB   : 25387008 .. 25552896
// ---------------------------------------------------------------------------
extern "C" void kernel_launch(void* const* d_in, const int* in_sizes, int n_in,
                              void* d_out, int out_size, void* d_ws, size_t ws_size,
                              hipStream_t stream) {
    const float* x       = (const float*)d_in[0];
    const float* dconv_w = (const float*)d_in[1];
    const float* dconv_b = (const float*)d_in[2];
    const float* off_w   = (const float*)d_in[3];
    const float* off_b   = (const float*)d_in[4];
    const float* def_w   = (const float*)d_in[5];
    const float* def_b   = (const float*)d_in[6];
    float* out = (float*)d_out;

    char* ws = (char*)d_ws;
    short* xb16 = (short*)(ws);
    short* x3b  = (short*)(ws + 12582912);
    short* wB1  = (short*)(ws + 25165824);
    short* wB2  = (short*)(ws + 25331712);
    short* wB   = (short*)(ws + 25387008);

    k_repack<<<324, 256, 0, stream>>>(dconv_w, off_w, def_w, wB1, wB2, wB);
    k_transpose<<<(BD*HWD)/64, 256, 0, stream>>>(x, xb16);
    k_conv1<<<(BD*HWD)/256, 512, 0, stream>>>(x, xb16, wB1, dconv_b, x3b);
    k_deform<<<(BD*HWD)/256, 512, 0, stream>>>(x3b, wB2, off_b, wB, def_b, out);
}